// Round 8
// baseline (162.359 us; speedup 1.0000x reference)
//
#include <hip/hip_runtime.h>
#include <hip/hip_bf16.h>
#include <stdint.h>

// SequentialMLP: E=8, H=1024, F=1024, T=16384, Tpe=2048
#define T_TOK 16384
#define H_DIM 1024
#define F_DIM 1024
#define E_NUM 8
#define TPE   2048

typedef unsigned short u16;
typedef __attribute__((ext_vector_type(8))) short bf16x8;   // 8 bf16 (4 VGPRs)
typedef __attribute__((ext_vector_type(4))) float f32x4;    // MFMA accumulator
typedef __attribute__((ext_vector_type(8))) u16 u16x8;

__device__ __forceinline__ u16 f2bf(float x) {
  unsigned int u = __float_as_uint(x);
  u = (u + 0x7fffu + ((u >> 16) & 1u)) >> 16;   // RNE
  return (u16)u;
}

// async global->LDS, 16B per lane. LDS dest = wave-uniform base + lane*16.
#define GLD16(gp, lp)                                                          \
  __builtin_amdgcn_global_load_lds(                                            \
      (const __attribute__((address_space(1))) void*)(gp),                     \
      (__attribute__((address_space(3))) void*)(lp), 16, 0, 0)

// ================================================================= prep pass
__global__ __launch_bounds__(256) void cvt_f32_bf16(
    const float* __restrict__ src, u16* __restrict__ dst, int n8) {
  int stride = gridDim.x * blockDim.x;
  for (int i = blockIdx.x * blockDim.x + threadIdx.x; i < n8; i += stride) {
    const float4* s = (const float4*)(src + (size_t)i * 8);
    float4 a = s[0], b = s[1];
    u16x8 o;
    o[0] = f2bf(a.x); o[1] = f2bf(a.y); o[2] = f2bf(a.z); o[3] = f2bf(a.w);
    o[4] = f2bf(b.x); o[5] = f2bf(b.y); o[6] = f2bf(b.z); o[7] = f2bf(b.w);
    *(u16x8*)(dst + (size_t)i * 8) = o;
  }
}

// batched [E][R][C] f32 -> [E][C][R] bf16 tiled transpose (64x64 tiles)
__global__ __launch_bounds__(256) void transpose_cvt(
    const float* __restrict__ src, u16* __restrict__ dst, int R, int C) {
  __shared__ float tile[64][65];
  int nCt = C >> 6, nRt = R >> 6;
  int per = nCt * nRt;
  int b = blockIdx.x;
  int e = b / per;
  int r2 = b - e * per;
  int rt = r2 / nCt, ct = r2 - rt * nCt;
  const float* s = src + (size_t)e * R * C + (size_t)(rt << 6) * C + (ct << 6);
  int t = threadIdx.x;
  int lr = t >> 4, lc = (t & 15) << 2;
#pragma unroll
  for (int i = 0; i < 4; i++) {
    float4 v = *(const float4*)(s + (size_t)(lr + i * 16) * C + lc);
    tile[lr + i * 16][lc + 0] = v.x;
    tile[lr + i * 16][lc + 1] = v.y;
    tile[lr + i * 16][lc + 2] = v.z;
    tile[lr + i * 16][lc + 3] = v.w;
  }
  __syncthreads();
  u16* d = dst + (size_t)e * C * R + (size_t)(ct << 6) * R + (rt << 6);
  int orow = t >> 2, ok = (t & 3) << 4;
  u16x8 o0, o1;
#pragma unroll
  for (int i = 0; i < 8; i++) o0[i] = f2bf(tile[ok + i][orow]);
#pragma unroll
  for (int i = 0; i < 8; i++) o1[i] = f2bf(tile[ok + 8 + i][orow]);
  *(u16x8*)(d + (size_t)orow * R + ok) = o0;
  *(u16x8*)(d + (size_t)orow * R + ok + 8) = o1;
}

// ====================================================== 256x256 GEMM, BK=64
// 8 waves (2Mx4N), 512 thr, LDS 128KB double-buffered.
// Swizzle byte ^= ((row&7)<<4) via inverse-swizzled GLOBAL source (linear LDS
// dest, rule 21) + swizzled ds_read offset.
//
// ROUND-8: barrier-free compute region. Evidence (r2..r7): per-phase barriers
// serialize LDS and MFMA pipes (phase time == read+write+mfma SUM). Fix:
// 2 barriers per K-tile total, one 64-MFMA compute region with zero syncs ->
// waves skew; one wave's ds_reads overlap another's MFMAs (m114 mechanism).
// Stage for tile t+1 issued a full K-tile (~2500cy) ahead of its vmcnt(8)
// (counted: 8 newer loads in flight, in-order retirement; never 0 in loop).
// Buffer safety: STAGE(db) targets the buffer computed 2 tiles ago, with a
// barrier between its last reader and the stage issue.

#define MFMA(a, b, c) __builtin_amdgcn_mfma_f32_16x16x32_bf16((a), (b), (c), 0, 0, 0)

#define PF_A(db, q, d) GLD16(aP[q] + (d), sm + (db) * 32768 + (q) * 8192 + tid * 16)
#define PF_B(db, q, d) GLD16(bP[q] + (d), sm + 65536 + (db) * 32768 + (q) * 8192 + tid * 16)

#define STAGE(db, off)                                                         \
  PF_B(db, 0, off); PF_B(db, 1, off); PF_B(db, 2, off); PF_B(db, 3, off);      \
  PF_A(db, 0, off); PF_A(db, 1, off); PF_A(db, 2, off); PF_A(db, 3, off);

#define VMW(N) asm volatile("s_waitcnt vmcnt(" #N ")" ::: "memory");

// one K-tile: 2 k-steps; per k-step read 8 A-frags + 4 B-frags, 32 MFMA.
// No barriers/sched fences inside: compiler + wave-skew do the overlap.
#define COMPUTE(b)                                                             \
  _Pragma("unroll") for (int ks_ = 0; ks_ < 2; ++ks_) {                        \
    bf16x8 aF[8], bF[4];                                                       \
    _Pragma("unroll") for (int m_ = 0; m_ < 8; ++m_)                           \
        aF[m_] = *(const bf16x8*)(sm + (b) * 32768 + aRowBase + m_ * 2048 +    \
                                  koff[ks_]);                                  \
    _Pragma("unroll") for (int n_ = 0; n_ < 4; ++n_)                           \
        bF[n_] = *(const bf16x8*)(sm + 65536 + (b) * 32768 + bRowBase +        \
                                  n_ * 2048 + koff[ks_]);                      \
    __builtin_amdgcn_s_setprio(1);                                             \
    _Pragma("unroll") for (int n_ = 0; n_ < 4; ++n_)                           \
    _Pragma("unroll") for (int m_ = 0; m_ < 8; ++m_)                           \
        acc[m_][n_] = MFMA(aF[m_], bF[n_], acc[m_][n_]);                       \
    __builtin_amdgcn_s_setprio(0);                                             \
  }

#define KLOOP_BODY                                                             \
  STAGE(0, 0)                            /* tile 0 -> buf0 */                  \
  for (int it = 0; it < 7; ++it) {                                             \
    __builtin_amdgcn_s_barrier();        /* buf1 readers (tile 2it-1) done */  \
    STAGE(1, 64)                         /* tile 2it+1 -> buf1 */              \
    VMW(8)                               /* tile 2it's 8 loads retired */      \
    __builtin_amdgcn_s_barrier();        /* buf0 contents visible to all */    \
    COMPUTE(0)                           /* tile 2it */                        \
    __builtin_amdgcn_s_barrier();                                              \
    STAGE(0, 128)                        /* tile 2it+2 -> buf0 */              \
    VMW(8)                                                                     \
    __builtin_amdgcn_s_barrier();                                              \
    COMPUTE(1)                           /* tile 2it+1 */                      \
    _Pragma("unroll") for (int q_ = 0; q_ < 4; ++q_) {                         \
      aP[q_] += 128; bP[q_] += 128;                                            \
    }                                                                          \
  }                                                                            \
  /* tail: tiles 14,15 (pointers at tile-14 base) */                           \
  __builtin_amdgcn_s_barrier();                                                \
  STAGE(1, 64)                           /* tile 15 -> buf1 */                 \
  VMW(8)                                                                       \
  __builtin_amdgcn_s_barrier();                                                \
  COMPUTE(0)                             /* tile 14 */                         \
  __builtin_amdgcn_s_barrier();                                                \
  VMW(0)                                                                       \
  __builtin_amdgcn_s_barrier();                                                \
  COMPUTE(1)                             /* tile 15 */

// ---------------------------------------------------------------- GEMM1+GLU
__global__ __launch_bounds__(512, 2) void gemm1_8p(
    const u16* __restrict__ xbf, const u16* __restrict__ w1t,
    const float* __restrict__ b1, const float* __restrict__ probs,
    u16* __restrict__ abf) {
  extern __shared__ char sm[];
  const int tid = threadIdx.x;
  const int lane = tid & 63;
  const int wid = tid >> 6;
  const int wm = wid >> 2, wn = wid & 3;
  const int bid = blockIdx.x;
  const int e = bid & 7;          // expert -> XCD pinning (round-robin bid%8)
  const int inner = bid >> 3;
  const int mt = inner >> 3, ct = inner & 7;
  const int tokBase = e * TPE + mt * 256;
  const int c0 = ct * 128;
  const int lrow = lane & 15, lkhi = lane >> 4;

  const u16* aP[4]; const u16* bP[4];
#pragma unroll
  for (int q = 0; q < 4; ++q) {
    int lin = q * 8192 + tid * 16;
    int lg = lin ^ (((lin >> 7) & 7) << 4);   // inverse swizzle (involution)
    int row = lg >> 7, kk = (lg & 127) >> 1;
    aP[q] = xbf + (size_t)(tokBase + row) * H_DIM + kk;
    // B row nn: alternate 32-blocks gate/lin so each wave owns matching pairs
    int col = (((row >> 5) & 1) << 10) + c0 + ((row >> 6) << 5) + (row & 31);
    bP[q] = w1t + (size_t)(e * 2 * F_DIM + col) * H_DIM + kk;
  }
  const int aRowBase = (wm * 128 + lrow) * 128;
  const int bRowBase = (wn * 64 + lrow) * 128;
  int koff[2];
#pragma unroll
  for (int ks = 0; ks < 2; ++ks)
    koff[ks] = ((ks << 6) | (lkhi << 4)) ^ ((lane & 7) << 4);

  f32x4 acc[8][4];
#pragma unroll
  for (int i = 0; i < 8; ++i)
#pragma unroll
    for (int j = 0; j < 4; ++j) acc[i][j] = f32x4{0.f, 0.f, 0.f, 0.f};

  KLOOP_BODY

  // epilogue: a = silu(gate+b1g) * (lin+b1l+1) * p -> bf16
#pragma unroll
  for (int j = 0; j < 2; ++j) {
    int cf = c0 + wn * 32 + j * 16 + lrow;
    float gb = b1[e * 2 * F_DIM + cf];
    float lb = b1[e * 2 * F_DIM + F_DIM + cf];
#pragma unroll
    for (int i = 0; i < 8; ++i) {
      int trow = tokBase + wm * 128 + i * 16 + lkhi * 4;
#pragma unroll
      for (int r = 0; r < 4; ++r) {
        float g = acc[i][j][r] + gb;
        float l = acc[i][j + 2][r] + lb + 1.0f;
        float p = probs[trow + r];
        float sig = 1.0f / (1.0f + __expf(-g));
        abf[(size_t)(trow + r) * F_DIM + cf] = f2bf(g * sig * l * p);
      }
    }
  }
}

// ---------------------------------------------------------------- GEMM2
__global__ __launch_bounds__(512, 2) void gemm2_8p(
    const u16* __restrict__ abf, const u16* __restrict__ w2t,
    const float* __restrict__ b2, float* __restrict__ out) {
  extern __shared__ char sm[];
  const int tid = threadIdx.x;
  const int lane = tid & 63;
  const int wid = tid >> 6;
  const int wm = wid >> 2, wn = wid & 3;
  const int bid = blockIdx.x;
  const int e = bid & 7;
  const int inner = bid >> 3;
  const int mt = inner >> 2, nt = inner & 3;
  const int tokBase = e * TPE + mt * 256;
  const int h0 = nt * 256;
  const int lrow = lane & 15, lkhi = lane >> 4;

  const u16* aP[4]; const u16* bP[4];
#pragma unroll
  for (int q = 0; q < 4; ++q) {
    int lin = q * 8192 + tid * 16;
    int lg = lin ^ (((lin >> 7) & 7) << 4);
    int row = lg >> 7, kk = (lg & 127) >> 1;
    aP[q] = abf + (size_t)(tokBase + row) * F_DIM + kk;
    bP[q] = w2t + (size_t)(e * H_DIM + h0 + row) * F_DIM + kk;
  }
  const int aRowBase = (wm * 128 + lrow) * 128;
  const int bRowBase = (wn * 64 + lrow) * 128;
  int koff[2];
#pragma unroll
  for (int ks = 0; ks < 2; ++ks)
    koff[ks] = ((ks << 6) | (lkhi << 4)) ^ ((lane & 7) << 4);

  f32x4 acc[8][4];
#pragma unroll
  for (int i = 0; i < 8; ++i)
#pragma unroll
    for (int j = 0; j < 4; ++j) acc[i][j] = f32x4{0.f, 0.f, 0.f, 0.f};

  KLOOP_BODY

#pragma unroll
  for (int j = 0; j < 4; ++j) {
    int h = h0 + wn * 64 + j * 16 + lrow;
    float bb = b2[e * H_DIM + h];
#pragma unroll
    for (int i = 0; i < 8; ++i) {
      int trow = tokBase + wm * 128 + i * 16 + lkhi * 4;
#pragma unroll
      for (int r = 0; r < 4; ++r)
        out[(size_t)(trow + r) * H_DIM + h] = acc[i][j][r] + bb;
    }
  }
}

// ---------------------------------------------------------------- launch
extern "C" void kernel_launch(void* const* d_in, const int* in_sizes, int n_in,
                              void* d_out, int out_size, void* d_ws,
                              size_t ws_size, hipStream_t stream) {
  const float* x     = (const float*)d_in[0];
  // d_in[1] tokens_per_expert: uniform (T/E) by construction, unused
  const float* probs = (const float*)d_in[2];
  const float* W1    = (const float*)d_in[3];
  const float* b1    = (const float*)d_in[4];
  const float* W2    = (const float*)d_in[5];
  const float* b2    = (const float*)d_in[6];
  float* out = (float*)d_out;

  // workspace: xbf[T,H] 32MB | w1t[E,2F,H] 32MB | w2t[E,H,F] 16MB | abf 32MB
  if (ws_size < 117440512u) return;
  char* ws = (char*)d_ws;
  u16* xbf = (u16*)(ws);
  u16* w1t = (u16*)(ws + 33554432);
  u16* w2t = (u16*)(ws + 67108864);
  u16* abf = (u16*)(ws + 83886080);

  (void)hipFuncSetAttribute(reinterpret_cast<const void*>(gemm1_8p),
                            hipFuncAttributeMaxDynamicSharedMemorySize, 131072);
  (void)hipFuncSetAttribute(reinterpret_cast<const void*>(gemm2_8p),
                            hipFuncAttributeMaxDynamicSharedMemorySize, 131072);

  cvt_f32_bf16<<<2048, 256, 0, stream>>>(x, xbf, (T_TOK * H_DIM) / 8);
  transpose_cvt<<<E_NUM * (2 * F_DIM / 64) * (H_DIM / 64), 256, 0, stream>>>(
      W1, w1t, H_DIM, 2 * F_DIM);
  transpose_cvt<<<E_NUM * (H_DIM / 64) * (F_DIM / 64), 256, 0, stream>>>(
      W2, w2t, F_DIM, H_DIM);
  gemm1_8p<<<E_NUM * 8 * 8, 512, 131072, stream>>>(xbf, w1t, b1, probs, abf);
  gemm2_8p<<<E_NUM * 8 * 4, 512, 131072, stream>>>(abf, w2t, b2, out);
}

// Round 9
// 150.758 us; speedup vs baseline: 1.0770x; 1.0770x over previous
//
#include <hip/hip_runtime.h>
#include <hip/hip_bf16.h>
#include <stdint.h>

// SequentialMLP: E=8, H=1024, F=1024, T=16384, Tpe=2048
#define T_TOK 16384
#define H_DIM 1024
#define F_DIM 1024
#define E_NUM 8
#define TPE   2048

typedef unsigned short u16;
typedef __attribute__((ext_vector_type(8))) short bf16x8;   // 8 bf16 (4 VGPRs)
typedef __attribute__((ext_vector_type(4))) float f32x4;    // MFMA accumulator
typedef __attribute__((ext_vector_type(8))) u16 u16x8;

__device__ __forceinline__ u16 f2bf(float x) {
  unsigned int u = __float_as_uint(x);
  u = (u + 0x7fffu + ((u >> 16) & 1u)) >> 16;   // RNE
  return (u16)u;
}

// async global->LDS, 16B per lane. LDS dest = wave-uniform base + lane*16.
#define GLD16(gp, lp)                                                          \
  __builtin_amdgcn_global_load_lds(                                            \
      (const __attribute__((address_space(1))) void*)(gp),                     \
      (__attribute__((address_space(3))) void*)(lp), 16, 0, 0)

// ================================================================= prep pass
// ROUND-9: ONE kernel, 10240 EQUAL-WORK blocks (16KB in / 8KB out each):
//   [0,4096)      x f32->bf16, flat-contiguous 16KB chunk per block
//   [4096,8192)   W1 64x64 transpose tiles (e,rt,ct)
//   [8192,10240)  W2 64x64 transpose tiles
// r3's fused prep failed from UNEQUAL roles (cvt blocks did 4x the work ->
// tail imbalance); uniform per-block work removes that, and 5->3 launches
// removes 2 graph-replay gaps.
__global__ __launch_bounds__(256) void prep_all(
    const float* __restrict__ x, const float* __restrict__ W1,
    const float* __restrict__ W2, u16* __restrict__ xbf,
    u16* __restrict__ w1t, u16* __restrict__ w2t) {
  __shared__ float tile[64][65];
  const int bid = blockIdx.x;
  const int t = threadIdx.x;

  if (bid < 4096) {
    // flat cvt: block covers f32 [bid*4096, +4096); thread: 16 consecutive
    size_t base = (size_t)bid * 4096 + (size_t)t * 16;
    const float4* s = (const float4*)(x + base);
    float4 v0 = s[0], v1 = s[1], v2 = s[2], v3 = s[3];
    u16x8 o0, o1;
    o0[0] = f2bf(v0.x); o0[1] = f2bf(v0.y); o0[2] = f2bf(v0.z); o0[3] = f2bf(v0.w);
    o0[4] = f2bf(v1.x); o0[5] = f2bf(v1.y); o0[6] = f2bf(v1.z); o0[7] = f2bf(v1.w);
    o1[0] = f2bf(v2.x); o1[1] = f2bf(v2.y); o1[2] = f2bf(v2.z); o1[3] = f2bf(v2.w);
    o1[4] = f2bf(v3.x); o1[5] = f2bf(v3.y); o1[6] = f2bf(v3.z); o1[7] = f2bf(v3.w);
    *(u16x8*)(xbf + base) = o0;
    *(u16x8*)(xbf + base + 8) = o1;
    return;
  }

  const float* src; u16* dst; int R, C, e, rt, ct;
  if (bid < 8192) {
    int id = bid - 4096;
    e = id >> 9; int r2 = id & 511; rt = r2 >> 5; ct = r2 & 31;
    src = W1; dst = w1t; R = H_DIM; C = 2 * F_DIM;
  } else {
    int id = bid - 8192;
    e = id >> 8; int r2 = id & 255; rt = r2 >> 4; ct = r2 & 15;
    src = W2; dst = w2t; R = F_DIM; C = H_DIM;
  }
  const float* s = src + (size_t)e * R * C + (size_t)(rt << 6) * C + (ct << 6);
  int lr = t >> 4, lc = (t & 15) << 2;
#pragma unroll
  for (int i = 0; i < 4; i++) {
    float4 v = *(const float4*)(s + (size_t)(lr + i * 16) * C + lc);
    tile[lr + i * 16][lc + 0] = v.x;
    tile[lr + i * 16][lc + 1] = v.y;
    tile[lr + i * 16][lc + 2] = v.z;
    tile[lr + i * 16][lc + 3] = v.w;
  }
  __syncthreads();
  u16* d = dst + (size_t)e * C * R + (size_t)(ct << 6) * R + (rt << 6);
  int orow = t >> 2, ok = (t & 3) << 4;
  u16x8 o0, o1;
#pragma unroll
  for (int i = 0; i < 8; i++) o0[i] = f2bf(tile[ok + i][orow]);
#pragma unroll
  for (int i = 0; i < 8; i++) o1[i] = f2bf(tile[ok + 8 + i][orow]);
  *(u16x8*)(d + (size_t)orow * R + ok) = o0;
  *(u16x8*)(d + (size_t)orow * R + ok + 8) = o1;
}

// ====================================================== 8-phase 256x256 GEMM
// ROUND-5 structure restored verbatim (best measured: gemm1 71.0us):
// BM=BN=256, BK=64, 8 waves (2Mx4N), 512 thr, LDS 128KB double-buffered.
// Swizzle byte ^= ((row&7)<<4) via inverse-swizzled GLOBAL source (linear LDS
// dest, rule 21) + swizzled ds_read offset. Reads in consumption order, no
// forced lgkmcnt drain; ONE barrier per phase. Prefetch ledger:
// p0/p1: t1.A  p2/p3: t0'.B  p4/p5: t0'.A  p6/p7: t1'.B ;
// vmcnt(4) after MFMA of p3 & p7 (counted, never 0 in steady state).

#define DSA(b, mi)                                                             \
  _Pragma("unroll") for (int m2_ = 0; m2_ < 2; ++m2_)                          \
  _Pragma("unroll") for (int ks_ = 0; ks_ < 2; ++ks_)                          \
      aF[m2_][ks_] = *(const bf16x8*)(sm + (b) * 32768 + aRowBase +            \
                                      ((mi) * 2 + m2_) * 2048 + koff[ks_]);

#define DSB(b)                                                                 \
  _Pragma("unroll") for (int n_ = 0; n_ < 4; ++n_)                             \
  _Pragma("unroll") for (int ks_ = 0; ks_ < 2; ++ks_)                          \
      bF[n_][ks_] = *(const bf16x8*)(sm + 65536 + (b) * 32768 + bRowBase +     \
                                     n_ * 2048 + koff[ks_]);

// n-outer so MFMA consumption order matches read issue order
#define MFMA16(mi)                                                             \
  _Pragma("unroll") for (int n_ = 0; n_ < 4; ++n_)                             \
  _Pragma("unroll") for (int m2_ = 0; m2_ < 2; ++m2_)                          \
  _Pragma("unroll") for (int ks_ = 0; ks_ < 2; ++ks_)                          \
      acc[(mi) * 2 + m2_][n_] = __builtin_amdgcn_mfma_f32_16x16x32_bf16(       \
          aF[m2_][ks_], bF[n_][ks_], acc[(mi) * 2 + m2_][n_], 0, 0, 0);

#define PF_A(db, q, d) GLD16(aP[q] + (d), sm + (db) * 32768 + (q) * 8192 + tid * 16)
#define PF_B(db, q, d) GLD16(bP[q] + (d), sm + 65536 + (db) * 32768 + (q) * 8192 + tid * 16)

#define PHASE(b, mi, PFC, WTC)                                                 \
  do {                                                                         \
    DSA(b, mi);                                                                \
    if ((mi) == 0) { DSB(b); }                                                 \
    PFC                                                                        \
    __builtin_amdgcn_s_setprio(1);                                             \
    MFMA16(mi);                                                                \
    __builtin_amdgcn_s_setprio(0);                                             \
    WTC                                                                        \
    __builtin_amdgcn_s_barrier();                                              \
  } while (0)

#define KLOOP_BODY                                                             \
  PF_B(0, 0, 0); PF_B(0, 1, 0); PF_B(0, 2, 0); PF_B(0, 3, 0);                  \
  PF_A(0, 0, 0); PF_A(0, 1, 0); PF_A(0, 2, 0); PF_A(0, 3, 0);                  \
  PF_B(1, 0, 64); PF_B(1, 1, 64); PF_B(1, 2, 64); PF_B(1, 3, 64);              \
  asm volatile("s_waitcnt vmcnt(4)" ::: "memory");                             \
  __builtin_amdgcn_s_barrier();                                                \
  for (int it = 0; it < 7; ++it) {                                             \
    PHASE(0, 0, PF_A(1, 0, 64); PF_A(1, 1, 64);, );                            \
    PHASE(0, 1, PF_A(1, 2, 64); PF_A(1, 3, 64);, );                            \
    PHASE(0, 2, PF_B(0, 0, 128); PF_B(0, 1, 128);, );                          \
    PHASE(0, 3, PF_B(0, 2, 128); PF_B(0, 3, 128);,                             \
          asm volatile("s_waitcnt vmcnt(4)" ::: "memory"););                   \
    PHASE(1, 0, PF_A(0, 0, 128); PF_A(0, 1, 128);, );                          \
    PHASE(1, 1, PF_A(0, 2, 128); PF_A(0, 3, 128);, );                          \
    PHASE(1, 2, PF_B(1, 0, 192); PF_B(1, 1, 192);, );                          \
    PHASE(1, 3, PF_B(1, 2, 192); PF_B(1, 3, 192);,                             \
          asm volatile("s_waitcnt vmcnt(4)" ::: "memory"););                   \
    _Pragma("unroll") for (int q_ = 0; q_ < 4; ++q_) {                         \
      aP[q_] += 128; bP[q_] += 128;                                            \
    }                                                                          \
  }                                                                            \
  PHASE(0, 0, PF_A(1, 0, 64); PF_A(1, 1, 64);, );                              \
  PHASE(0, 1, PF_A(1, 2, 64); PF_A(1, 3, 64);, );                              \
  PHASE(0, 2, , );                                                             \
  PHASE(0, 3, , asm volatile("s_waitcnt vmcnt(0)" ::: "memory"););             \
  PHASE(1, 0, , );                                                             \
  PHASE(1, 1, , );                                                             \
  PHASE(1, 2, , );                                                             \
  PHASE(1, 3, , );

// ---------------------------------------------------------------- GEMM1+GLU
__global__ __launch_bounds__(512, 2) void gemm1_8p(
    const u16* __restrict__ xbf, const u16* __restrict__ w1t,
    const float* __restrict__ b1, const float* __restrict__ probs,
    u16* __restrict__ abf) {
  extern __shared__ char sm[];
  const int tid = threadIdx.x;
  const int lane = tid & 63;
  const int wid = tid >> 6;
  const int wm = wid >> 2, wn = wid & 3;
  const int bid = blockIdx.x;
  const int e = bid & 7;          // expert -> XCD pinning (round-robin bid%8)
  const int inner = bid >> 3;
  const int mt = inner >> 3, ct = inner & 7;
  const int tokBase = e * TPE + mt * 256;
  const int c0 = ct * 128;
  const int lrow = lane & 15, lkhi = lane >> 4;

  const u16* aP[4]; const u16* bP[4];
#pragma unroll
  for (int q = 0; q < 4; ++q) {
    int lin = q * 8192 + tid * 16;
    int lg = lin ^ (((lin >> 7) & 7) << 4);   // inverse swizzle (involution)
    int row = lg >> 7, kk = (lg & 127) >> 1;
    aP[q] = xbf + (size_t)(tokBase + row) * H_DIM + kk;
    // B row nn: alternate 32-blocks gate/lin so each wave owns matching pairs
    int col = (((row >> 5) & 1) << 10) + c0 + ((row >> 6) << 5) + (row & 31);
    bP[q] = w1t + (size_t)(e * 2 * F_DIM + col) * H_DIM + kk;
  }
  const int aRowBase = (wm * 128 + lrow) * 128;
  const int bRowBase = (wn * 64 + lrow) * 128;
  int koff[2];
#pragma unroll
  for (int ks = 0; ks < 2; ++ks)
    koff[ks] = ((ks << 6) | (lkhi << 4)) ^ ((lane & 7) << 4);

  f32x4 acc[8][4];
#pragma unroll
  for (int i = 0; i < 8; ++i)
#pragma unroll
    for (int j = 0; j < 4; ++j) acc[i][j] = f32x4{0.f, 0.f, 0.f, 0.f};
  bf16x8 aF[2][2], bF[4][2];

  KLOOP_BODY

  // epilogue: a = silu(gate+b1g) * (lin+b1l+1) * p -> bf16
#pragma unroll
  for (int j = 0; j < 2; ++j) {
    int cf = c0 + wn * 32 + j * 16 + lrow;
    float gb = b1[e * 2 * F_DIM + cf];
    float lb = b1[e * 2 * F_DIM + F_DIM + cf];
#pragma unroll
    for (int i = 0; i < 8; ++i) {
      int trow = tokBase + wm * 128 + i * 16 + lkhi * 4;
#pragma unroll
      for (int r = 0; r < 4; ++r) {
        float g = acc[i][j][r] + gb;
        float l = acc[i][j + 2][r] + lb + 1.0f;
        float p = probs[trow + r];
        float sig = 1.0f / (1.0f + __expf(-g));
        abf[(size_t)(trow + r) * F_DIM + cf] = f2bf(g * sig * l * p);
      }
    }
  }
}

// ---------------------------------------------------------------- GEMM2
__global__ __launch_bounds__(512, 2) void gemm2_8p(
    const u16* __restrict__ abf, const u16* __restrict__ w2t,
    const float* __restrict__ b2, float* __restrict__ out) {
  extern __shared__ char sm[];
  const int tid = threadIdx.x;
  const int lane = tid & 63;
  const int wid = tid >> 6;
  const int wm = wid >> 2, wn = wid & 3;
  const int bid = blockIdx.x;
  const int e = bid & 7;
  const int inner = bid >> 3;
  const int mt = inner >> 2, nt = inner & 3;
  const int tokBase = e * TPE + mt * 256;
  const int h0 = nt * 256;
  const int lrow = lane & 15, lkhi = lane >> 4;

  const u16* aP[4]; const u16* bP[4];
#pragma unroll
  for (int q = 0; q < 4; ++q) {
    int lin = q * 8192 + tid * 16;
    int lg = lin ^ (((lin >> 7) & 7) << 4);
    int row = lg >> 7, kk = (lg & 127) >> 1;
    aP[q] = abf + (size_t)(tokBase + row) * F_DIM + kk;
    bP[q] = w2t + (size_t)(e * H_DIM + h0 + row) * F_DIM + kk;
  }
  const int aRowBase = (wm * 128 + lrow) * 128;
  const int bRowBase = (wn * 64 + lrow) * 128;
  int koff[2];
#pragma unroll
  for (int ks = 0; ks < 2; ++ks)
    koff[ks] = ((ks << 6) | (lkhi << 4)) ^ ((lane & 7) << 4);

  f32x4 acc[8][4];
#pragma unroll
  for (int i = 0; i < 8; ++i)
#pragma unroll
    for (int j = 0; j < 4; ++j) acc[i][j] = f32x4{0.f, 0.f, 0.f, 0.f};
  bf16x8 aF[2][2], bF[4][2];

  KLOOP_BODY

#pragma unroll
  for (int j = 0; j < 4; ++j) {
    int h = h0 + wn * 64 + j * 16 + lrow;
    float bb = b2[e * H_DIM + h];
#pragma unroll
    for (int i = 0; i < 8; ++i) {
      int trow = tokBase + wm * 128 + i * 16 + lkhi * 4;
#pragma unroll
      for (int r = 0; r < 4; ++r)
        out[(size_t)(trow + r) * H_DIM + h] = acc[i][j][r] + bb;
    }
  }
}

// ---------------------------------------------------------------- launch
extern "C" void kernel_launch(void* const* d_in, const int* in_sizes, int n_in,
                              void* d_out, int out_size, void* d_ws,
                              size_t ws_size, hipStream_t stream) {
  const float* x     = (const float*)d_in[0];
  // d_in[1] tokens_per_expert: uniform (T/E) by construction, unused
  const float* probs = (const float*)d_in[2];
  const float* W1    = (const float*)d_in[3];
  const float* b1    = (const float*)d_in[4];
  const float* W2    = (const float*)d_in[5];
  const float* b2    = (const float*)d_in[6];
  float* out = (float*)d_out;

  // workspace: xbf[T,H] 32MB | w1t[E,2F,H] 32MB | w2t[E,H,F] 16MB | abf 32MB
  if (ws_size < 117440512u) return;
  char* ws = (char*)d_ws;
  u16* xbf = (u16*)(ws);
  u16* w1t = (u16*)(ws + 33554432);
  u16* w2t = (u16*)(ws + 67108864);
  u16* abf = (u16*)(ws + 83886080);

  (void)hipFuncSetAttribute(reinterpret_cast<const void*>(gemm1_8p),
                            hipFuncAttributeMaxDynamicSharedMemorySize, 131072);
  (void)hipFuncSetAttribute(reinterpret_cast<const void*>(gemm2_8p),
                            hipFuncAttributeMaxDynamicSharedMemorySize, 131072);

  prep_all<<<10240, 256, 0, stream>>>(x, W1, W2, xbf, w1t, w2t);
  gemm1_8p<<<E_NUM * 8 * 8, 512, 131072, stream>>>(xbf, w1t, b1, probs, abf);
  gemm2_8p<<<E_NUM * 8 * 4, 512, 131072, stream>>>(abf, w2t, b2, out);
}